// Round 12
// baseline (623.448 us; speedup 1.0000x reference)
//
#include <hip/hip_runtime.h>
#include <hip/hip_bf16.h>

#define N_TOK 8192
#define DM 768
#define DFF 2048
#define NE 8
#define SHARED_BASE 17408   // routed padded slots max 16384 + 8*127 -> 17408
#define TOTAL_ROWS 25600

typedef __attribute__((ext_vector_type(8))) __bf16 bf16x8;
typedef __attribute__((ext_vector_type(4))) float f32x4;

__device__ __forceinline__ unsigned short f2bf(float f) {
  union { float f; unsigned u; } a; a.f = f;
  unsigned r = a.u + 0x7FFFu + ((a.u >> 16) & 1u);
  return (unsigned short)(r >> 16);
}

__device__ __forceinline__ float bfu(unsigned short u) {
  union { unsigned u; float f; } x; x.u = (unsigned)u << 16; return x.f;
}

__device__ __forceinline__ void gload16(const void* g, void* l) {
  __builtin_amdgcn_global_load_lds((const __attribute__((address_space(1))) void*)g,
                                   (__attribute__((address_space(3))) void*)l, 16, 0, 0);
}

// ---------------- prep kernels ----------------

// all 27 weight matrices transposed+converted in one launch (z selects matrix).
__global__ void transpose_all_kernel(
    const float* __restrict__ w1, const float* __restrict__ w3, const float* __restrict__ w2,
    const float* __restrict__ sw1, const float* __restrict__ sw3, const float* __restrict__ sw2,
    unsigned short* __restrict__ w1T, unsigned short* __restrict__ w3T,
    unsigned short* __restrict__ w2T,
    unsigned short* __restrict__ sw1T, unsigned short* __restrict__ sw3T,
    unsigned short* __restrict__ sw2T) {
  __shared__ float tile[64][65];
  const int z = blockIdx.z;
  const float* s; unsigned short* d; int R, C; bool swapRC;
  if (z < 8)       { s = w1 + (size_t)z * DM * DFF;        d = w1T + (size_t)z * DM * DFF;        R = DM;  C = DFF; swapRC = false; }
  else if (z < 16) { s = w3 + (size_t)(z - 8) * DM * DFF;  d = w3T + (size_t)(z - 8) * DM * DFF;  R = DM;  C = DFF; swapRC = false; }
  else if (z < 24) { s = w2 + (size_t)(z - 16) * DFF * DM; d = w2T + (size_t)(z - 16) * DFF * DM; R = DFF; C = DM;  swapRC = true;  }
  else if (z == 24){ s = sw1; d = sw1T; R = DM;  C = DFF; swapRC = false; }
  else if (z == 25){ s = sw3; d = sw3T; R = DM;  C = DFF; swapRC = false; }
  else             { s = sw2; d = sw2T; R = DFF; C = DM;  swapRC = true;  }
  int r0 = (swapRC ? blockIdx.x : blockIdx.y) * 64;
  int c0 = (swapRC ? blockIdx.y : blockIdx.x) * 64;
  int tx = threadIdx.x & 63, ty = threadIdx.x >> 6;
#pragma unroll
  for (int i = 0; i < 16; i++) {
    int row = i * 4 + ty;
    tile[row][tx] = s[(size_t)(r0 + row) * C + c0 + tx];
  }
  __syncthreads();
  int tx2 = threadIdx.x & 31, ty8 = threadIdx.x >> 5;  // pair-col, 0..7
#pragma unroll
  for (int i = 0; i < 8; i++) {
    int row = i * 8 + ty8;   // 0..63 (c-row index within tile)
    ushort2 v;
    v.x = f2bf(tile[tx2 * 2][row]);
    v.y = f2bf(tile[tx2 * 2 + 1][row]);
    *(ushort2*)&d[(size_t)(c0 + row) * R + r0 + tx2 * 2] = v;
  }
}

// gate: 4 waves x 4 tokens each, gw transposed in LDS, fp64 accumulation, no atomics.
// Also emits xb (bf16 x) — fused cvt pass.
__global__ __launch_bounds__(256) void gate_kernel(
    const float* __restrict__ x, const float* __restrict__ gw,
    float* __restrict__ probs, int* __restrict__ idxo, unsigned short* __restrict__ xb) {
  __shared__ float gws[8][768];
  const int tid = threadIdx.x;
  for (int i = tid; i < DM * 2; i += 256) {
    float4 v = ((const float4*)gw)[i];
    int dd = i >> 1;
    int e0 = (i & 1) * 4;
    gws[e0 + 0][dd] = v.x; gws[e0 + 1][dd] = v.y;
    gws[e0 + 2][dd] = v.z; gws[e0 + 3][dd] = v.w;
  }
  __syncthreads();
  const int lane = tid & 63, wv = tid >> 6;
  const int tok0 = blockIdx.x * 16 + wv * 4;
  for (int i = 0; i < 4; i++) {
    const int n = tok0 + i;
    const float* xr = x + (size_t)n * DM;
    float xv[12];
#pragma unroll
    for (int it = 0; it < 12; it++) xv[it] = xr[it * 64 + lane];
#pragma unroll
    for (int it = 0; it < 12; it++) xb[(size_t)n * DM + it * 64 + lane] = f2bf(xv[it]);
    double acc[8];
#pragma unroll
    for (int e = 0; e < 8; e++) {
      double a = 0.0;
#pragma unroll
      for (int it = 0; it < 12; it++) a += (double)xv[it] * (double)gws[e][it * 64 + lane];
      acc[e] = a;
    }
#pragma unroll
    for (int off = 32; off > 0; off >>= 1)
#pragma unroll
      for (int e = 0; e < 8; e++) acc[e] += __shfl_xor(acc[e], off);
    if (lane == 0) {
      int e0 = 0; double v0 = acc[0];
#pragma unroll
      for (int e = 1; e < 8; e++) if (acc[e] > v0) { v0 = acc[e]; e0 = e; }
      int e1 = -1; double v1 = -1e300;
#pragma unroll
      for (int e = 0; e < 8; e++) if (e != e0 && acc[e] > v1) { v1 = acc[e]; e1 = e; }
      double p0 = 1.0 / (1.0 + exp(v1 - v0));
      probs[n * 2 + 0] = (float)p0;
      probs[n * 2 + 1] = (float)(1.0 - p0);
      idxo[n * 2 + 0] = e0;
      idxo[n * 2 + 1] = e1;
    }
  }
}

// route: single block, deterministic prefix-scan scatter (128-aligned segments).
__global__ __launch_bounds__(256) void route_kernel(
    const int* __restrict__ idxo,
    int* __restrict__ cnt, int* __restrict__ offs,
    int* __restrict__ list, int* __restrict__ slt) {
  __shared__ int lcnt[256][8];
  __shared__ int lstart[256][8];
  __shared__ int base[8];
  const int t = threadIdx.x;
#pragma unroll
  for (int e = 0; e < 8; e++) lcnt[t][e] = 0;
  __syncthreads();
  const int i0 = t * 64;
  for (int j = 0; j < 64; j++) {
    int e = idxo[i0 + j];
    lcnt[t][e]++;
  }
  __syncthreads();
  if (t < 8) {
    int run = 0;
    for (int tt = 0; tt < 256; tt++) { lstart[tt][t] = run; run += lcnt[tt][t]; }
    base[t] = run;
  }
  __syncthreads();
  if (t == 0) {
    int cum = 0;
    for (int e = 0; e < 8; e++) {
      int tot = base[e];
      cnt[e] = tot; offs[e] = cum;
      base[e] = cum;
      cum += (tot + 127) & ~127;
    }
    offs[8] = cum;
  }
  __syncthreads();
#pragma unroll
  for (int e = 0; e < 8; e++) lcnt[t][e] = base[e] + lstart[t][e];
  for (int j = 0; j < 64; j++) {
    int i = i0 + j;
    int e = idxo[i];
    int pos = lcnt[t][e]++;
    list[pos] = i >> 1;
    slt[i] = pos;
  }
}

// ---------------- GEMM1: H = silu(x@w1) * (x@w3), bf16 out ----------------
// block tile 128(M) x 64(F), BK=64, 256 threads (4 waves, 2x2), wave tile 64x32.
// m97-style 2-barrier structure (877 TF measured). XCD-swizzled so all 32 f-tiles
// of one by-group land on one XCD -> shared A-panel hits that XCD's L2.
__global__ __launch_bounds__(256, 2) void gemm1_kernel(
    const char* __restrict__ xb,     // bf16 [8192][768]
    const char* __restrict__ w1T,    // bf16 [8][2048][768]
    const char* __restrict__ w3T,
    const char* __restrict__ sw1T,   // bf16 [2048][768]
    const char* __restrict__ sw3T,
    const int* __restrict__ list, const int* __restrict__ cnt, const int* __restrict__ offs,
    unsigned short* __restrict__ Hb) // bf16 [25600][2048]
{
  __shared__ unsigned short Al[128 * 64];
  __shared__ unsigned short B1l[64 * 64];
  __shared__ unsigned short B3l[64 * 64];

  // XCD-aware swizzle (bijective: nwg = 32*576 = 18432, %8==0)
  int lin = blockIdx.y * 32 + blockIdx.x;
  lin = (lin & 7) * (18432 / 8) + (lin >> 3);
  const int by = lin >> 5;          // 0..575
  const int f0 = (lin & 31) * 64;

  const int tid = threadIdx.x;
  const int lane = tid & 63;
  const int wv = tid >> 6;
  const int wm = wv >> 1, wn = wv & 1;
  const int wflat = tid & ~63;

  const char *w1p, *w3p;
  int base_slot, tbase, cnt_e, offs_e = 0;
  const bool is_shared = (by >= 512);
  if (!is_shared) {
    int e = by >> 6, t = by & 63;
    cnt_e = cnt[e];
    if (t * 128 >= cnt_e) return;
    offs_e = offs[e];
    base_slot = offs_e + t * 128;
    tbase = t * 128;
    w1p = w1T + (size_t)e * DFF * DM * 2;
    w3p = w3T + (size_t)e * DFF * DM * 2;
  } else {
    int t = by - 512;
    base_slot = SHARED_BASE + t * 128;
    tbase = t * 128;
    cnt_e = 1 << 30;
    w1p = sw1T; w3p = sw3T;
  }

  const int brow = tid >> 3;  // 0..31
  const int bcol = tid & 7;

  size_t abase[4];
#pragma unroll
  for (int it = 0; it < 4; it++) {
    int row = it * 32 + brow;   // 0..127
    int tok;
    if (is_shared) tok = tbase + row;
    else {
      int ie = tbase + row;
      if (ie >= cnt_e) ie = cnt_e - 1;
      tok = list[offs_e + ie];
    }
    abase[it] = (size_t)tok * (DM * 2) + (size_t)((bcol ^ (row & 7)) << 4);
  }
  size_t bbase[2];
#pragma unroll
  for (int it = 0; it < 2; it++) {
    int row = it * 32 + brow;   // 0..63
    bbase[it] = (size_t)(f0 + row) * (DM * 2) + (size_t)((bcol ^ (row & 7)) << 4);
  }

  f32x4 acc1[4][2], acc3[4][2];
  const f32x4 z4 = {0.f, 0.f, 0.f, 0.f};
#pragma unroll
  for (int mi = 0; mi < 4; mi++)
#pragma unroll
    for (int ni = 0; ni < 2; ni++) { acc1[mi][ni] = z4; acc3[mi][ni] = z4; }

  const int ml = lane & 15, kg = lane >> 4;

  for (int ks = 0; ks < 12; ks++) {
#pragma unroll
    for (int it = 0; it < 4; it++)
      gload16(xb + abase[it] + ks * 128, (char*)Al + (size_t)((it * 256 + wflat) * 16));
#pragma unroll
    for (int it = 0; it < 2; it++) {
      gload16(w1p + bbase[it] + ks * 128, (char*)B1l + (size_t)((it * 256 + wflat) * 16));
      gload16(w3p + bbase[it] + ks * 128, (char*)B3l + (size_t)((it * 256 + wflat) * 16));
    }
    __syncthreads();
#pragma unroll
    for (int kk = 0; kk < 2; kk++) {
      const int kblk = kk * 4 + kg;
      bf16x8 af[4], b1f[2], b3f[2];
#pragma unroll
      for (int mi = 0; mi < 4; mi++) {
        int m = wm * 64 + mi * 16 + ml;
        af[mi] = *(const bf16x8*)((const char*)Al + m * 128 + ((kblk ^ (ml & 7)) << 4));
      }
#pragma unroll
      for (int ni = 0; ni < 2; ni++) {
        int nn = wn * 32 + ni * 16 + ml;
        int boff = nn * 128 + ((kblk ^ (ml & 7)) << 4);
        b1f[ni] = *(const bf16x8*)((const char*)B1l + boff);
        b3f[ni] = *(const bf16x8*)((const char*)B3l + boff);
      }
#pragma unroll
      for (int mi = 0; mi < 4; mi++)
#pragma unroll
        for (int ni = 0; ni < 2; ni++) {
          acc1[mi][ni] = __builtin_amdgcn_mfma_f32_16x16x32_bf16(af[mi], b1f[ni], acc1[mi][ni], 0, 0, 0);
          acc3[mi][ni] = __builtin_amdgcn_mfma_f32_16x16x32_bf16(af[mi], b3f[ni], acc3[mi][ni], 0, 0, 0);
        }
    }
    __syncthreads();
  }

#pragma unroll
  for (int mi = 0; mi < 4; mi++) {
#pragma unroll
    for (int ni = 0; ni < 2; ni++) {
#pragma unroll
      for (int r = 0; r < 4; r++) {
        int row = wm * 64 + mi * 16 + (lane >> 4) * 4 + r;
        int col = f0 + wn * 32 + ni * 16 + ml;
        float h1 = acc1[mi][ni][r], h3 = acc3[mi][ni][r];
        float s = h1 / (1.0f + expf(-h1));
        Hb[(size_t)(base_slot + row) * DFF + col] = f2bf(s * h3);
      }
    }
  }
}

// ---------------- GEMM2: routed -> Ob (bf16 plain stores), shared -> out ----------------
// block tile 128(M) x 256(D), BK=64 (32 steps), 512 threads = 8 waves (2M x 4N), wave 64x64.
// XCD-swizzled so the 3 d-splits of one by land on one XCD -> H rows fetched once per XCD.
__global__ __launch_bounds__(512, 4) void gemm2_kernel(
    const char* __restrict__ Hb,     // bf16 [25600][2048]
    const char* __restrict__ w2T,    // bf16 [8][768][2048]
    const char* __restrict__ sw2T,   // bf16 [768][2048]
    const int* __restrict__ cnt, const int* __restrict__ offs,
    unsigned short* __restrict__ Obh, // bf16 [17408][768]
    float* __restrict__ out)          // fp32 [8192][768]
{
  __shared__ unsigned short Al[128 * 64];   // 16 KB
  __shared__ unsigned short Bl[256 * 64];   // 32 KB

  // XCD-aware swizzle (bijective: nwg = 3*576 = 1728, %8==0)
  int lin = blockIdx.y * 3 + blockIdx.x;
  lin = (lin & 7) * (1728 / 8) + (lin >> 3);
  const int by = lin / 3;
  const int d0 = (lin - by * 3) * 256;

  const int tid = threadIdx.x;
  const int lane = tid & 63;
  const int wv = tid >> 6;          // 0..7
  const int wm = wv >> 2;           // 0..1
  const int wn = wv & 3;            // 0..3
  const int ml = lane & 15, kg = lane >> 4;

  const char* w2p;
  int base_slot, tbase, cnt_e;
  const bool is_shared = (by >= 512);
  if (!is_shared) {
    int e = by >> 6, t = by & 63;
    cnt_e = cnt[e];
    if (t * 128 >= cnt_e) return;
    base_slot = offs[e] + t * 128;
    tbase = t * 128;
    w2p = w2T + (size_t)e * DM * DFF * 2;
  } else {
    int t = by - 512;
    base_slot = SHARED_BASE + t * 128;
    tbase = t * 128;
    cnt_e = 1 << 30;
    w2p = sw2T;
  }

  const int srow = tid >> 3, schk = tid & 7;
  size_t abase[2];
#pragma unroll
  for (int it = 0; it < 2; it++) {
    int row = it * 64 + srow;  // 0..127
    abase[it] = (size_t)(base_slot + row) * (DFF * 2) + (size_t)((schk ^ (row & 7)) << 4);
  }
  size_t bbase[4];
#pragma unroll
  for (int it = 0; it < 4; it++) {
    int row = it * 64 + srow;  // 0..255
    bbase[it] = (size_t)(d0 + row) * (DFF * 2) + (size_t)((schk ^ (row & 7)) << 4);
  }

  f32x4 acc[4][4];
  const f32x4 z4 = {0.f, 0.f, 0.f, 0.f};
#pragma unroll
  for (int mi = 0; mi < 4; mi++)
#pragma unroll
    for (int nj = 0; nj < 4; nj++) acc[mi][nj] = z4;

  for (int ks = 0; ks < 32; ks++) {
#pragma unroll
    for (int it = 0; it < 2; it++)
      gload16(Hb + abase[it] + ks * 128, (char*)Al + (size_t)((it * 512 + tid) * 16));
#pragma unroll
    for (int it = 0; it < 4; it++)
      gload16(w2p + bbase[it] + ks * 128, (char*)Bl + (size_t)((it * 512 + tid) * 16));
    __syncthreads();
#pragma unroll
    for (int kk = 0; kk < 2; kk++) {
      const int kblk = kk * 4 + kg;
      const int chk = (kblk ^ (ml & 7)) << 4;
      bf16x8 af[4], bfr[4];
#pragma unroll
      for (int mi = 0; mi < 4; mi++) {
        int m = wm * 64 + mi * 16 + ml;
        af[mi] = *(const bf16x8*)((const char*)Al + m * 128 + chk);
      }
#pragma unroll
      for (int nj = 0; nj < 4; nj++) {
        int nn = wn * 64 + nj * 16 + ml;
        bfr[nj] = *(const bf16x8*)((const char*)Bl + nn * 128 + chk);
      }
#pragma unroll
      for (int mi = 0; mi < 4; mi++)
#pragma unroll
        for (int nj = 0; nj < 4; nj++)
          acc[mi][nj] = __builtin_amdgcn_mfma_f32_16x16x32_bf16(af[mi], bfr[nj], acc[mi][nj], 0, 0, 0);
    }
    __syncthreads();
  }

#pragma unroll
  for (int mi = 0; mi < 4; mi++) {
#pragma unroll
    for (int r = 0; r < 4; r++) {
      int row = wm * 64 + mi * 16 + (lane >> 4) * 4 + r;
      if (is_shared) {
        float* orow = out + (size_t)(tbase + row) * DM + d0;
#pragma unroll
        for (int nj = 0; nj < 4; nj++)
          orow[wn * 64 + nj * 16 + ml] = acc[mi][nj][r];
      } else {
        unsigned short* orow = Obh + (size_t)(base_slot + row) * DM + d0;
#pragma unroll
        for (int nj = 0; nj < 4; nj++)
          orow[wn * 64 + nj * 16 + ml] = f2bf(acc[mi][nj][r]);
      }
    }
  }
}

// combine: out[n] += p0*Ob[s0] + p1*Ob[s1] (Ob bf16), fp32 out.
__global__ __launch_bounds__(192) void combine_kernel(
    const unsigned short* __restrict__ Obh, const int* __restrict__ slt,
    const float* __restrict__ probs, float4* __restrict__ out4) {
  const int n = blockIdx.x;
  const int t = threadIdx.x;
  const int s0 = slt[2 * n], s1 = slt[2 * n + 1];
  const float p0 = probs[2 * n], p1 = probs[2 * n + 1];
  ushort4 b4 = *(const ushort4*)(Obh + (size_t)s0 * DM + t * 4);
  ushort4 c4 = *(const ushort4*)(Obh + (size_t)s1 * DM + t * 4);
  float4 a = out4[(size_t)n * 192 + t];
  a.x += p0 * bfu(b4.x) + p1 * bfu(c4.x);
  a.y += p0 * bfu(b4.y) + p1 * bfu(c4.y);
  a.z += p0 * bfu(b4.z) + p1 * bfu(c4.z);
  a.w += p0 * bfu(b4.w) + p1 * bfu(c4.w);
  out4[(size_t)n * 192 + t] = a;
}

// ---------------- launch ----------------

extern "C" void kernel_launch(void* const* d_in, const int* in_sizes, int n_in,
                              void* d_out, int out_size, void* d_ws, size_t ws_size,
                              hipStream_t stream) {
  const float* x   = (const float*)d_in[0];
  const float* gw  = (const float*)d_in[1];
  const float* w1  = (const float*)d_in[2];
  const float* w3  = (const float*)d_in[3];
  const float* w2  = (const float*)d_in[4];
  const float* sw1 = (const float*)d_in[5];
  const float* sw3 = (const float*)d_in[6];
  const float* sw2 = (const float*)d_in[7];
  float* out = (float*)d_out;
  char* ws = (char*)d_ws;

  char* xb   = ws;                       // 12,582,912
  char* w2T  = xb + 12582912;            // 25,165,824
  char* sw2T = w2T + 25165824;           //  3,145,728
  char* U    = sw2T + 3145728;           // 56,623,104 (union region)
  char* w1T  = U;                        // 25,165,824
  char* w3T  = w1T + 25165824;           // 25,165,824
  char* sw1T = w3T + 25165824;           //  3,145,728
  char* sw3T = sw1T + 3145728;           //  3,145,728
  char* Ob   = U;                        // 26,738,688 bf16 (aliases w1T.. after gemm1)
  char* Hb   = U + 56623104;             // 104,857,600
  char* probs= Hb + 104857600;           // 65,536
  char* idxo = probs + 65536;            // 65,536
  char* lst  = idxo + 65536;             // 69,632
  char* slt  = lst + 69632;              // 69,632
  char* cntb = slt + 69632;              // 64
  char* offb = cntb + 64;                // 64

  transpose_all_kernel<<<dim3(32, 12, 27), 256, 0, stream>>>(
      w1, w3, w2, sw1, sw3, sw2,
      (unsigned short*)w1T, (unsigned short*)w3T, (unsigned short*)w2T,
      (unsigned short*)sw1T, (unsigned short*)sw3T, (unsigned short*)sw2T);

  gate_kernel<<<512, 256, 0, stream>>>(x, gw, (float*)probs, (int*)idxo, (unsigned short*)xb);
  route_kernel<<<1, 256, 0, stream>>>((const int*)idxo,
                                      (int*)cntb, (int*)offb, (int*)lst, (int*)slt);

  gemm1_kernel<<<dim3(32, 576), 256, 0, stream>>>(xb, w1T, w3T, sw1T, sw3T,
      (const int*)lst, (const int*)cntb, (const int*)offb, (unsigned short*)Hb);

  gemm2_kernel<<<dim3(3, 576), 512, 0, stream>>>(Hb, w2T, sw2T,
      (const int*)cntb, (const int*)offb, (unsigned short*)Ob, out);

  combine_kernel<<<N_TOK, 192, 0, stream>>>((const unsigned short*)Ob, (const int*)slt,
                                            (const float*)probs, (float4*)out);
}

// Round 13
// 374.692 us; speedup vs baseline: 1.6639x; 1.6639x over previous
//
#include <hip/hip_runtime.h>
#include <hip/hip_bf16.h>

#define N_TOK 8192
#define DM 768
#define DFF 2048
#define NE 8
#define SHARED_BASE 17408   // routed padded slots max 16384 + 8*127 -> 17408
#define TOTAL_ROWS 25600

typedef __attribute__((ext_vector_type(8))) __bf16 bf16x8;
typedef __attribute__((ext_vector_type(4))) float f32x4;

__device__ __forceinline__ unsigned short f2bf(float f) {
  union { float f; unsigned u; } a; a.f = f;
  unsigned r = a.u + 0x7FFFu + ((a.u >> 16) & 1u);
  return (unsigned short)(r >> 16);
}

__device__ __forceinline__ float bfu(unsigned short u) {
  union { unsigned u; float f; } x; x.u = (unsigned)u << 16; return x.f;
}

__device__ __forceinline__ void gload16(const void* g, void* l) {
  __builtin_amdgcn_global_load_lds((const __attribute__((address_space(1))) void*)g,
                                   (__attribute__((address_space(3))) void*)l, 16, 0, 0);
}

// ---------------- prep kernels ----------------

// all 27 weight matrices transposed+converted in one launch (z selects matrix).
__global__ void transpose_all_kernel(
    const float* __restrict__ w1, const float* __restrict__ w3, const float* __restrict__ w2,
    const float* __restrict__ sw1, const float* __restrict__ sw3, const float* __restrict__ sw2,
    unsigned short* __restrict__ w1T, unsigned short* __restrict__ w3T,
    unsigned short* __restrict__ w2T,
    unsigned short* __restrict__ sw1T, unsigned short* __restrict__ sw3T,
    unsigned short* __restrict__ sw2T) {
  __shared__ float tile[64][65];
  const int z = blockIdx.z;
  const float* s; unsigned short* d; int R, C; bool swapRC;
  if (z < 8)       { s = w1 + (size_t)z * DM * DFF;        d = w1T + (size_t)z * DM * DFF;        R = DM;  C = DFF; swapRC = false; }
  else if (z < 16) { s = w3 + (size_t)(z - 8) * DM * DFF;  d = w3T + (size_t)(z - 8) * DM * DFF;  R = DM;  C = DFF; swapRC = false; }
  else if (z < 24) { s = w2 + (size_t)(z - 16) * DFF * DM; d = w2T + (size_t)(z - 16) * DFF * DM; R = DFF; C = DM;  swapRC = true;  }
  else if (z == 24){ s = sw1; d = sw1T; R = DM;  C = DFF; swapRC = false; }
  else if (z == 25){ s = sw3; d = sw3T; R = DM;  C = DFF; swapRC = false; }
  else             { s = sw2; d = sw2T; R = DFF; C = DM;  swapRC = true;  }
  int r0 = (swapRC ? blockIdx.x : blockIdx.y) * 64;
  int c0 = (swapRC ? blockIdx.y : blockIdx.x) * 64;
  int tx = threadIdx.x & 63, ty = threadIdx.x >> 6;
#pragma unroll
  for (int i = 0; i < 16; i++) {
    int row = i * 4 + ty;
    tile[row][tx] = s[(size_t)(r0 + row) * C + c0 + tx];
  }
  __syncthreads();
  int tx2 = threadIdx.x & 31, ty8 = threadIdx.x >> 5;  // pair-col, 0..7
#pragma unroll
  for (int i = 0; i < 8; i++) {
    int row = i * 8 + ty8;   // 0..63 (c-row index within tile)
    ushort2 v;
    v.x = f2bf(tile[tx2 * 2][row]);
    v.y = f2bf(tile[tx2 * 2 + 1][row]);
    *(ushort2*)&d[(size_t)(c0 + row) * R + r0 + tx2 * 2] = v;
  }
}

// gate: 4 waves x 4 tokens each, gw transposed in LDS, fp64 accumulation, no atomics.
// Also emits xb (bf16 x) — fused cvt pass.
__global__ __launch_bounds__(256) void gate_kernel(
    const float* __restrict__ x, const float* __restrict__ gw,
    float* __restrict__ probs, int* __restrict__ idxo, unsigned short* __restrict__ xb) {
  __shared__ float gws[8][768];
  const int tid = threadIdx.x;
  for (int i = tid; i < DM * 2; i += 256) {
    float4 v = ((const float4*)gw)[i];
    int dd = i >> 1;
    int e0 = (i & 1) * 4;
    gws[e0 + 0][dd] = v.x; gws[e0 + 1][dd] = v.y;
    gws[e0 + 2][dd] = v.z; gws[e0 + 3][dd] = v.w;
  }
  __syncthreads();
  const int lane = tid & 63, wv = tid >> 6;
  const int tok0 = blockIdx.x * 16 + wv * 4;
  for (int i = 0; i < 4; i++) {
    const int n = tok0 + i;
    const float* xr = x + (size_t)n * DM;
    float xv[12];
#pragma unroll
    for (int it = 0; it < 12; it++) xv[it] = xr[it * 64 + lane];
#pragma unroll
    for (int it = 0; it < 12; it++) xb[(size_t)n * DM + it * 64 + lane] = f2bf(xv[it]);
    double acc[8];
#pragma unroll
    for (int e = 0; e < 8; e++) {
      double a = 0.0;
#pragma unroll
      for (int it = 0; it < 12; it++) a += (double)xv[it] * (double)gws[e][it * 64 + lane];
      acc[e] = a;
    }
#pragma unroll
    for (int off = 32; off > 0; off >>= 1)
#pragma unroll
      for (int e = 0; e < 8; e++) acc[e] += __shfl_xor(acc[e], off);
    if (lane == 0) {
      int e0 = 0; double v0 = acc[0];
#pragma unroll
      for (int e = 1; e < 8; e++) if (acc[e] > v0) { v0 = acc[e]; e0 = e; }
      int e1 = -1; double v1 = -1e300;
#pragma unroll
      for (int e = 0; e < 8; e++) if (e != e0 && acc[e] > v1) { v1 = acc[e]; e1 = e; }
      double p0 = 1.0 / (1.0 + exp(v1 - v0));
      probs[n * 2 + 0] = (float)p0;
      probs[n * 2 + 1] = (float)(1.0 - p0);
      idxo[n * 2 + 0] = e0;
      idxo[n * 2 + 1] = e1;
    }
  }
}

// route: single block, deterministic prefix-scan scatter (128-aligned segments).
__global__ __launch_bounds__(256) void route_kernel(
    const int* __restrict__ idxo,
    int* __restrict__ cnt, int* __restrict__ offs,
    int* __restrict__ list, int* __restrict__ slt) {
  __shared__ int lcnt[256][8];
  __shared__ int lstart[256][8];
  __shared__ int base[8];
  const int t = threadIdx.x;
#pragma unroll
  for (int e = 0; e < 8; e++) lcnt[t][e] = 0;
  __syncthreads();
  const int i0 = t * 64;
  for (int j = 0; j < 64; j++) {
    int e = idxo[i0 + j];
    lcnt[t][e]++;
  }
  __syncthreads();
  if (t < 8) {
    int run = 0;
    for (int tt = 0; tt < 256; tt++) { lstart[tt][t] = run; run += lcnt[tt][t]; }
    base[t] = run;
  }
  __syncthreads();
  if (t == 0) {
    int cum = 0;
    for (int e = 0; e < 8; e++) {
      int tot = base[e];
      cnt[e] = tot; offs[e] = cum;
      base[e] = cum;
      cum += (tot + 127) & ~127;
    }
    offs[8] = cum;
  }
  __syncthreads();
#pragma unroll
  for (int e = 0; e < 8; e++) lcnt[t][e] = base[e] + lstart[t][e];
  for (int j = 0; j < 64; j++) {
    int i = i0 + j;
    int e = idxo[i];
    int pos = lcnt[t][e]++;
    list[pos] = i >> 1;
    slt[i] = pos;
  }
}

// ---------------- GEMM1: H = silu(x@w1) * (x@w3), bf16 out ----------------
// block tile 128(M) x 64(F), BK=64, 256 threads (4 waves, 2x2), wave tile 64x32.
// Proven m97-style 2-barrier structure: 32KB LDS -> high TLP. 178 us measured.
__global__ __launch_bounds__(256, 2) void gemm1_kernel(
    const char* __restrict__ xb,     // bf16 [8192][768]
    const char* __restrict__ w1T,    // bf16 [8][2048][768]
    const char* __restrict__ w3T,
    const char* __restrict__ sw1T,   // bf16 [2048][768]
    const char* __restrict__ sw3T,
    const int* __restrict__ list, const int* __restrict__ cnt, const int* __restrict__ offs,
    unsigned short* __restrict__ Hb) // bf16 [25600][2048]
{
  __shared__ unsigned short Al[128 * 64];
  __shared__ unsigned short B1l[64 * 64];
  __shared__ unsigned short B3l[64 * 64];

  const int by = blockIdx.y;
  const int f0 = blockIdx.x * 64;
  const int tid = threadIdx.x;
  const int lane = tid & 63;
  const int wv = tid >> 6;
  const int wm = wv >> 1, wn = wv & 1;
  const int wflat = tid & ~63;

  const char *w1p, *w3p;
  int base_slot, tbase, cnt_e, offs_e = 0;
  const bool is_shared = (by >= 512);
  if (!is_shared) {
    int e = by >> 6, t = by & 63;
    cnt_e = cnt[e];
    if (t * 128 >= cnt_e) return;
    offs_e = offs[e];
    base_slot = offs_e + t * 128;
    tbase = t * 128;
    w1p = w1T + (size_t)e * DFF * DM * 2;
    w3p = w3T + (size_t)e * DFF * DM * 2;
  } else {
    int t = by - 512;
    base_slot = SHARED_BASE + t * 128;
    tbase = t * 128;
    cnt_e = 1 << 30;
    w1p = sw1T; w3p = sw3T;
  }

  const int brow = tid >> 3;  // 0..31
  const int bcol = tid & 7;

  size_t abase[4];
#pragma unroll
  for (int it = 0; it < 4; it++) {
    int row = it * 32 + brow;   // 0..127
    int tok;
    if (is_shared) tok = tbase + row;
    else {
      int ie = tbase + row;
      if (ie >= cnt_e) ie = cnt_e - 1;
      tok = list[offs_e + ie];
    }
    abase[it] = (size_t)tok * (DM * 2) + (size_t)((bcol ^ (row & 7)) << 4);
  }
  size_t bbase[2];
#pragma unroll
  for (int it = 0; it < 2; it++) {
    int row = it * 32 + brow;   // 0..63
    bbase[it] = (size_t)(f0 + row) * (DM * 2) + (size_t)((bcol ^ (row & 7)) << 4);
  }

  f32x4 acc1[4][2], acc3[4][2];
  const f32x4 z4 = {0.f, 0.f, 0.f, 0.f};
#pragma unroll
  for (int mi = 0; mi < 4; mi++)
#pragma unroll
    for (int ni = 0; ni < 2; ni++) { acc1[mi][ni] = z4; acc3[mi][ni] = z4; }

  const int ml = lane & 15, kg = lane >> 4;

  for (int ks = 0; ks < 12; ks++) {
#pragma unroll
    for (int it = 0; it < 4; it++)
      gload16(xb + abase[it] + ks * 128, (char*)Al + (size_t)((it * 256 + wflat) * 16));
#pragma unroll
    for (int it = 0; it < 2; it++) {
      gload16(w1p + bbase[it] + ks * 128, (char*)B1l + (size_t)((it * 256 + wflat) * 16));
      gload16(w3p + bbase[it] + ks * 128, (char*)B3l + (size_t)((it * 256 + wflat) * 16));
    }
    __syncthreads();
#pragma unroll
    for (int kk = 0; kk < 2; kk++) {
      const int kblk = kk * 4 + kg;
      bf16x8 af[4], b1f[2], b3f[2];
#pragma unroll
      for (int mi = 0; mi < 4; mi++) {
        int m = wm * 64 + mi * 16 + ml;
        af[mi] = *(const bf16x8*)((const char*)Al + m * 128 + ((kblk ^ (ml & 7)) << 4));
      }
#pragma unroll
      for (int ni = 0; ni < 2; ni++) {
        int nn = wn * 32 + ni * 16 + ml;
        int boff = nn * 128 + ((kblk ^ (ml & 7)) << 4);
        b1f[ni] = *(const bf16x8*)((const char*)B1l + boff);
        b3f[ni] = *(const bf16x8*)((const char*)B3l + boff);
      }
#pragma unroll
      for (int mi = 0; mi < 4; mi++)
#pragma unroll
        for (int ni = 0; ni < 2; ni++) {
          acc1[mi][ni] = __builtin_amdgcn_mfma_f32_16x16x32_bf16(af[mi], b1f[ni], acc1[mi][ni], 0, 0, 0);
          acc3[mi][ni] = __builtin_amdgcn_mfma_f32_16x16x32_bf16(af[mi], b3f[ni], acc3[mi][ni], 0, 0, 0);
        }
    }
    __syncthreads();
  }

#pragma unroll
  for (int mi = 0; mi < 4; mi++) {
#pragma unroll
    for (int ni = 0; ni < 2; ni++) {
#pragma unroll
      for (int r = 0; r < 4; r++) {
        int row = wm * 64 + mi * 16 + (lane >> 4) * 4 + r;
        int col = f0 + wn * 32 + ni * 16 + ml;
        float h1 = acc1[mi][ni][r], h3 = acc3[mi][ni][r];
        float s = h1 / (1.0f + expf(-h1));
        Hb[(size_t)(base_slot + row) * DFF + col] = f2bf(s * h3);
      }
    }
  }
}

// ---------------- GEMM2: routed -> Ob (bf16 plain stores), shared -> out ----------------
// block tile 128(M) x 256(D), BK=64 (32 steps), 512 threads = 8 waves (2M x 4N), wave 64x64.
__global__ __launch_bounds__(512, 4) void gemm2_kernel(
    const char* __restrict__ Hb,     // bf16 [25600][2048]
    const char* __restrict__ w2T,    // bf16 [8][768][2048]
    const char* __restrict__ sw2T,   // bf16 [768][2048]
    const int* __restrict__ cnt, const int* __restrict__ offs,
    unsigned short* __restrict__ Obh, // bf16 [17408][768]
    float* __restrict__ out)          // fp32 [8192][768]
{
  __shared__ unsigned short Al[128 * 64];   // 16 KB
  __shared__ unsigned short Bl[256 * 64];   // 32 KB

  const int by = blockIdx.y;
  const int d0 = blockIdx.x * 256;
  const int tid = threadIdx.x;
  const int lane = tid & 63;
  const int wv = tid >> 6;          // 0..7
  const int wm = wv >> 2;           // 0..1
  const int wn = wv & 3;            // 0..3
  const int ml = lane & 15, kg = lane >> 4;

  const char* w2p;
  int base_slot, tbase, cnt_e;
  const bool is_shared = (by >= 512);
  if (!is_shared) {
    int e = by >> 6, t = by & 63;
    cnt_e = cnt[e];
    if (t * 128 >= cnt_e) return;
    base_slot = offs[e] + t * 128;
    tbase = t * 128;
    w2p = w2T + (size_t)e * DM * DFF * 2;
  } else {
    int t = by - 512;
    base_slot = SHARED_BASE + t * 128;
    tbase = t * 128;
    cnt_e = 1 << 30;
    w2p = sw2T;
  }

  const int srow = tid >> 3, schk = tid & 7;
  size_t abase[2];
#pragma unroll
  for (int it = 0; it < 2; it++) {
    int row = it * 64 + srow;  // 0..127
    abase[it] = (size_t)(base_slot + row) * (DFF * 2) + (size_t)((schk ^ (row & 7)) << 4);
  }
  size_t bbase[4];
#pragma unroll
  for (int it = 0; it < 4; it++) {
    int row = it * 64 + srow;  // 0..255
    bbase[it] = (size_t)(d0 + row) * (DFF * 2) + (size_t)((schk ^ (row & 7)) << 4);
  }

  f32x4 acc[4][4];
  const f32x4 z4 = {0.f, 0.f, 0.f, 0.f};
#pragma unroll
  for (int mi = 0; mi < 4; mi++)
#pragma unroll
    for (int nj = 0; nj < 4; nj++) acc[mi][nj] = z4;

  for (int ks = 0; ks < 32; ks++) {
#pragma unroll
    for (int it = 0; it < 2; it++)
      gload16(Hb + abase[it] + ks * 128, (char*)Al + (size_t)((it * 512 + tid) * 16));
#pragma unroll
    for (int it = 0; it < 4; it++)
      gload16(w2p + bbase[it] + ks * 128, (char*)Bl + (size_t)((it * 512 + tid) * 16));
    __syncthreads();
#pragma unroll
    for (int kk = 0; kk < 2; kk++) {
      const int kblk = kk * 4 + kg;
      const int chk = (kblk ^ (ml & 7)) << 4;
      bf16x8 af[4], bfr[4];
#pragma unroll
      for (int mi = 0; mi < 4; mi++) {
        int m = wm * 64 + mi * 16 + ml;
        af[mi] = *(const bf16x8*)((const char*)Al + m * 128 + chk);
      }
#pragma unroll
      for (int nj = 0; nj < 4; nj++) {
        int nn = wn * 64 + nj * 16 + ml;
        bfr[nj] = *(const bf16x8*)((const char*)Bl + nn * 128 + chk);
      }
#pragma unroll
      for (int mi = 0; mi < 4; mi++)
#pragma unroll
        for (int nj = 0; nj < 4; nj++)
          acc[mi][nj] = __builtin_amdgcn_mfma_f32_16x16x32_bf16(af[mi], bfr[nj], acc[mi][nj], 0, 0, 0);
    }
    __syncthreads();
  }

#pragma unroll
  for (int mi = 0; mi < 4; mi++) {
#pragma unroll
    for (int r = 0; r < 4; r++) {
      int row = wm * 64 + mi * 16 + (lane >> 4) * 4 + r;
      if (is_shared) {
        float* orow = out + (size_t)(tbase + row) * DM + d0;
#pragma unroll
        for (int nj = 0; nj < 4; nj++)
          orow[wn * 64 + nj * 16 + ml] = acc[mi][nj][r];
      } else {
        unsigned short* orow = Obh + (size_t)(base_slot + row) * DM + d0;
#pragma unroll
        for (int nj = 0; nj < 4; nj++)
          orow[wn * 64 + nj * 16 + ml] = f2bf(acc[mi][nj][r]);
      }
    }
  }
}

// combine: out[n] += p0*Ob[s0] + p1*Ob[s1] (Ob bf16), fp32 out.
__global__ __launch_bounds__(192) void combine_kernel(
    const unsigned short* __restrict__ Obh, const int* __restrict__ slt,
    const float* __restrict__ probs, float4* __restrict__ out4) {
  const int n = blockIdx.x;
  const int t = threadIdx.x;
  const int s0 = slt[2 * n], s1 = slt[2 * n + 1];
  const float p0 = probs[2 * n], p1 = probs[2 * n + 1];
  ushort4 b4 = *(const ushort4*)(Obh + (size_t)s0 * DM + t * 4);
  ushort4 c4 = *(const ushort4*)(Obh + (size_t)s1 * DM + t * 4);
  float4 a = out4[(size_t)n * 192 + t];
  a.x += p0 * bfu(b4.x) + p1 * bfu(c4.x);
  a.y += p0 * bfu(b4.y) + p1 * bfu(c4.y);
  a.z += p0 * bfu(b4.z) + p1 * bfu(c4.z);
  a.w += p0 * bfu(b4.w) + p1 * bfu(c4.w);
  out4[(size_t)n * 192 + t] = a;
}

// ---------------- launch ----------------

extern "C" void kernel_launch(void* const* d_in, const int* in_sizes, int n_in,
                              void* d_out, int out_size, void* d_ws, size_t ws_size,
                              hipStream_t stream) {
  const float* x   = (const float*)d_in[0];
  const float* gw  = (const float*)d_in[1];
  const float* w1  = (const float*)d_in[2];
  const float* w3  = (const float*)d_in[3];
  const float* w2  = (const float*)d_in[4];
  const float* sw1 = (const float*)d_in[5];
  const float* sw3 = (const float*)d_in[6];
  const float* sw2 = (const float*)d_in[7];
  float* out = (float*)d_out;
  char* ws = (char*)d_ws;

  char* xb   = ws;                       // 12,582,912
  char* w2T  = xb + 12582912;            // 25,165,824
  char* sw2T = w2T + 25165824;           //  3,145,728
  char* U    = sw2T + 3145728;           // 56,623,104 (union region)
  char* w1T  = U;                        // 25,165,824
  char* w3T  = w1T + 25165824;           // 25,165,824
  char* sw1T = w3T + 25165824;           //  3,145,728
  char* sw3T = sw1T + 3145728;           //  3,145,728
  char* Ob   = U;                        // 26,738,688 bf16 (aliases w1T.. after gemm1)
  char* Hb   = U + 56623104;             // 104,857,600
  char* probs= Hb + 104857600;           // 65,536
  char* idxo = probs + 65536;            // 65,536
  char* lst  = idxo + 65536;             // 69,632
  char* slt  = lst + 69632;              // 69,632
  char* cntb = slt + 69632;              // 64
  char* offb = cntb + 64;                // 64

  transpose_all_kernel<<<dim3(32, 12, 27), 256, 0, stream>>>(
      w1, w3, w2, sw1, sw3, sw2,
      (unsigned short*)w1T, (unsigned short*)w3T, (unsigned short*)w2T,
      (unsigned short*)sw1T, (unsigned short*)sw3T, (unsigned short*)sw2T);

  gate_kernel<<<512, 256, 0, stream>>>(x, gw, (float*)probs, (int*)idxo, (unsigned short*)xb);
  route_kernel<<<1, 256, 0, stream>>>((const int*)idxo,
                                      (int*)cntb, (int*)offb, (int*)lst, (int*)slt);

  gemm1_kernel<<<dim3(32, 576), 256, 0, stream>>>(xb, w1T, w3T, sw1T, sw3T,
      (const int*)lst, (const int*)cntb, (const int*)offb, (unsigned short*)Hb);

  gemm2_kernel<<<dim3(3, 576), 512, 0, stream>>>(Hb, w2T, sw2T,
      (const int*)cntb, (const int*)offb, (unsigned short*)Ob, out);

  combine_kernel<<<N_TOK, 192, 0, stream>>>((const unsigned short*)Ob, (const int*)slt,
                                            (const float*)probs, (float4*)out);
}